// Round 2
// baseline (92.897 us; speedup 1.0000x reference)
//
#include <hip/hip_runtime.h>
#include <math.h>

#define BATCH   262144
#define CLUSTER 100

// Build a Lorentz boost matrix B = I - (g*mag)*nK + (g-1)*nK^2 analytically.
//   B[0][0]     = 1 + (g-1)
//   B[0][j+1]   = B[j+1][0] = -(g*mag)*n_j
//   B[i+1][j+1] = delta_ij + (g-1)*n_i*n_j
__device__ inline void boost_mat(float bx, float by, float bz, float B[4][4]) {
    float m2  = bx * bx + by * by + bz * bz;
    float mag = sqrtf(m2);
    float nx = bx / mag, ny = by / mag, nz = bz / mag;
    float g  = 1.0f / sqrtf(1.0f - mag * mag);
    float gm = g * mag;
    float gm1 = g - 1.0f;
    float n[3] = {nx, ny, nz};
    B[0][0] = 1.0f + gm1 * (nx * nx + ny * ny + nz * nz);
    for (int j = 0; j < 3; ++j) {
        B[0][j + 1] = -gm * n[j];
        B[j + 1][0] = -gm * n[j];
    }
    for (int i = 0; i < 3; ++i)
        for (int j = 0; j < 3; ++j)
            B[i + 1][j + 1] = ((i == j) ? 1.0f : 0.0f) + gm1 * n[i] * n[j];
}

// M_c[a][d] = sum_e BiM[a][e] * (W_c * BoM_c[e][d]); stored [c][a][d].
__global__ void build_M_kernel(const float* __restrict__ Bo,
                               const float* __restrict__ Bi,
                               const float* __restrict__ W,
                               float* __restrict__ M) {
    int c = threadIdx.x;
    if (c >= CLUSTER) return;

    float BiM[4][4];
    boost_mat(Bi[0], Bi[1], Bi[2], BiM);

    float BoM[4][4];
    boost_mat(Bo[c * 3 + 0], Bo[c * 3 + 1], Bo[c * 3 + 2], BoM);

    float w = W[c];
    for (int a = 0; a < 4; ++a)
        for (int d = 0; d < 4; ++d) {
            float s = 0.0f;
            for (int e = 0; e < 4; ++e)
                s += BiM[a][e] * (w * BoM[e][d]);
            M[c * 16 + a * 4 + d] = s;
        }
}

#define DOT4(mm, vv) ((mm).x*(vv).x + (mm).y*(vv).y + (mm).z*(vv).z + (mm).w*(vv).w)

// out[b][a] = sum_c sum_d M[c][a][d] * T[b][c][d]
// 4-lane group owns 4 rows; lane q handles clusters c = 4t+q for ALL 4 rows,
// so one 64B M read (LDS) serves 64B of T (global): 1:1 LDS:HBM traffic.
__global__ __launch_bounds__(256, 4) void lorentz_main_kernel(
        const float* __restrict__ T,
        const float* __restrict__ M,
        float* __restrict__ out) {
    __shared__ float sM[CLUSTER * 16];

    int tid = threadIdx.x;
    for (int i = tid; i < CLUSTER * 4; i += 256)
        ((float4*)sM)[i] = ((const float4*)M)[i];
    __syncthreads();

    int wave = tid >> 6;
    int lane = tid & 63;
    int q  = lane & 3;
    int g  = lane >> 2;
    // wave covers 64 rows: 16 groups x 4 rows
    long long rowBase = (long long)blockIdx.x * 256 + wave * 64 + g * 4;

    const float* T0 = T + rowBase * (CLUSTER * 4);

    float4 a0 = {0.f, 0.f, 0.f, 0.f};
    float4 a1 = a0, a2 = a0, a3 = a0;

    #pragma unroll 2
    for (int t = 0; t < 25; ++t) {
        int c = 4 * t + q;
        float4 v0 = *(const float4*)(T0 +    0 + c * 4);
        float4 v1 = *(const float4*)(T0 +  400 + c * 4);
        float4 v2 = *(const float4*)(T0 +  800 + c * 4);
        float4 v3 = *(const float4*)(T0 + 1200 + c * 4);
        const float4* m = (const float4*)(sM + c * 16);
        float4 m0 = m[0], m1 = m[1], m2 = m[2], m3 = m[3];

        a0.x += DOT4(m0, v0); a0.y += DOT4(m1, v0); a0.z += DOT4(m2, v0); a0.w += DOT4(m3, v0);
        a1.x += DOT4(m0, v1); a1.y += DOT4(m1, v1); a1.z += DOT4(m2, v1); a1.w += DOT4(m3, v1);
        a2.x += DOT4(m0, v2); a2.y += DOT4(m1, v2); a2.z += DOT4(m2, v2); a2.w += DOT4(m3, v2);
        a3.x += DOT4(m0, v3); a3.y += DOT4(m1, v3); a3.z += DOT4(m2, v3); a3.w += DOT4(m3, v3);
    }

    // reduce over the 4-lane group: every lane ends with the full sums
    #define RED(f) f += __shfl_xor(f, 1); f += __shfl_xor(f, 2);
    RED(a0.x) RED(a0.y) RED(a0.z) RED(a0.w)
    RED(a1.x) RED(a1.y) RED(a1.z) RED(a1.w)
    RED(a2.x) RED(a2.y) RED(a2.z) RED(a2.w)
    RED(a3.x) RED(a3.y) RED(a3.z) RED(a3.w)
    #undef RED

    // lane q writes row (rowBase + q): wave store is 1KB fully contiguous
    float4 o = a0;
    if (q == 1) o = a1;
    if (q == 2) o = a2;
    if (q == 3) o = a3;
    ((float4*)out)[rowBase + q] = o;
}

extern "C" void kernel_launch(void* const* d_in, const int* in_sizes, int n_in,
                              void* d_out, int out_size, void* d_ws, size_t ws_size,
                              hipStream_t stream) {
    const float* T  = (const float*)d_in[0];
    const float* Bo = (const float*)d_in[1];
    const float* Bi = (const float*)d_in[2];
    const float* W  = (const float*)d_in[3];
    // d_in[4] = K_mats (folded into analytic boost formula)

    float* M = (float*)d_ws;           // 1600 floats
    float* out = (float*)d_out;

    build_M_kernel<<<1, 128, 0, stream>>>(Bo, Bi, W, M);

    int blocks = BATCH / 256;          // 256 rows per block (4 waves x 64 rows)
    lorentz_main_kernel<<<blocks, 256, 0, stream>>>(T, M, out);
}

// Round 3
// 77.941 us; speedup vs baseline: 1.1919x; 1.1919x over previous
//
#include <hip/hip_runtime.h>
#include <math.h>

#define BATCH   262144
#define CLUSTER 100

// Analytic Lorentz boost matrix B = I - (g*mag)*nK + (g-1)*nK^2:
//   B[0][0]     = g
//   B[0][j+1]   = B[j+1][0] = -(g*mag)*n_j
//   B[i+1][j+1] = delta_ij + (g-1)*n_i*n_j
__device__ inline void boost_mat(float bx, float by, float bz, float B[4][4]) {
    float m2  = bx * bx + by * by + bz * bz;
    float mag = sqrtf(m2);
    float nx = bx / mag, ny = by / mag, nz = bz / mag;
    float g  = 1.0f / sqrtf(1.0f - mag * mag);
    float gm = g * mag;
    float gm1 = g - 1.0f;
    float n[3] = {nx, ny, nz};
    B[0][0] = 1.0f + gm1 * (nx * nx + ny * ny + nz * nz);
    for (int j = 0; j < 3; ++j) {
        B[0][j + 1] = -gm * n[j];
        B[j + 1][0] = -gm * n[j];
    }
    for (int i = 0; i < 3; ++i)
        for (int j = 0; j < 3; ++j)
            B[i + 1][j + 1] = ((i == j) ? 1.0f : 0.0f) + gm1 * n[i] * n[j];
}

#define DOT4(mm, vv) ((mm).x*(vv).x + (mm).y*(vv).y + (mm).z*(vv).z + (mm).w*(vv).w)

// out[b][a] = sum_c sum_d M[c][a][d] * T[b][c][d],  M_c = BiM @ (W_c * BoM_c)
// 8-lane group: lane q handles clusters c = 8t+q  -> each row-load instruction
// covers full 128B cache lines, 8 line-segments per VMEM instr (stride 1600B).
// Each group owns 2 rows (base+g, base+g+8): 16 rows per wave.
__global__ __launch_bounds__(256) void lorentz_fused_kernel(
        const float* __restrict__ T,
        const float* __restrict__ Bo,
        const float* __restrict__ Bi,
        const float* __restrict__ W,
        float* __restrict__ out) {
    __shared__ float sM[CLUSTER * 16];

    int tid = threadIdx.x;
    // Build all 100 M_c matrices in-block (kills the separate-kernel launch).
    if (tid < CLUSTER) {
        float BiM[4][4], BoM[4][4];
        boost_mat(Bi[0], Bi[1], Bi[2], BiM);
        boost_mat(Bo[tid * 3 + 0], Bo[tid * 3 + 1], Bo[tid * 3 + 2], BoM);
        float w = W[tid];
        for (int a = 0; a < 4; ++a)
            for (int d = 0; d < 4; ++d) {
                float s = 0.0f;
                for (int e = 0; e < 4; ++e)
                    s += BiM[a][e] * (w * BoM[e][d]);
                sM[tid * 16 + a * 4 + d] = s;
            }
    }
    __syncthreads();

    int wave = tid >> 6;
    int lane = tid & 63;
    int q = lane & 7;       // position in 8-lane group
    int g = lane >> 3;      // group 0..7
    long long base = (long long)blockIdx.x * 64 + wave * 16;
    long long row0 = base + g;
    long long row1 = base + g + 8;

    const float* P0 = T + row0 * (CLUSTER * 4);
    const float* P1 = T + row1 * (CLUSTER * 4);

    float4 a0 = {0.f, 0.f, 0.f, 0.f};
    float4 a1 = a0;

    #pragma unroll 4
    for (int t = 0; t < 12; ++t) {
        int c = 8 * t + q;
        float4 v0 = *(const float4*)(P0 + c * 4);
        float4 v1 = *(const float4*)(P1 + c * 4);
        const float4* m = (const float4*)(sM + c * 16);
        float4 m0 = m[0], m1 = m[1], m2 = m[2], m3 = m[3];
        a0.x += DOT4(m0, v0); a0.y += DOT4(m1, v0); a0.z += DOT4(m2, v0); a0.w += DOT4(m3, v0);
        a1.x += DOT4(m0, v1); a1.y += DOT4(m1, v1); a1.z += DOT4(m2, v1); a1.w += DOT4(m3, v1);
    }
    // tail: c = 96..99 handled by lanes q<4
    if (q < 4) {
        int c = 96 + q;
        float4 v0 = *(const float4*)(P0 + c * 4);
        float4 v1 = *(const float4*)(P1 + c * 4);
        const float4* m = (const float4*)(sM + c * 16);
        float4 m0 = m[0], m1 = m[1], m2 = m[2], m3 = m[3];
        a0.x += DOT4(m0, v0); a0.y += DOT4(m1, v0); a0.z += DOT4(m2, v0); a0.w += DOT4(m3, v0);
        a1.x += DOT4(m0, v1); a1.y += DOT4(m1, v1); a1.z += DOT4(m2, v1); a1.w += DOT4(m3, v1);
    }

    // butterfly reduce across the 8-lane group; all lanes end with full sums
    #define RED(f) f += __shfl_xor(f, 1); f += __shfl_xor(f, 2); f += __shfl_xor(f, 4);
    RED(a0.x) RED(a0.y) RED(a0.z) RED(a0.w)
    RED(a1.x) RED(a1.y) RED(a1.z) RED(a1.w)
    #undef RED

    // wave writes 16 consecutive rows (256B contiguous)
    if (q == 0) ((float4*)out)[row0] = a0;
    if (q == 1) ((float4*)out)[row1] = a1;
}

extern "C" void kernel_launch(void* const* d_in, const int* in_sizes, int n_in,
                              void* d_out, int out_size, void* d_ws, size_t ws_size,
                              hipStream_t stream) {
    const float* T  = (const float*)d_in[0];
    const float* Bo = (const float*)d_in[1];
    const float* Bi = (const float*)d_in[2];
    const float* W  = (const float*)d_in[3];
    // d_in[4] = K_mats (folded into analytic boost formula)

    float* out = (float*)d_out;

    int blocks = BATCH / 64;   // 64 rows per block (4 waves x 16 rows)
    lorentz_fused_kernel<<<blocks, 256, 0, stream>>>(T, Bo, Bi, W, out);
}